// Round 3
// baseline (758.896 us; speedup 1.0000x reference)
//
#include <hip/hip_runtime.h>
#include <stdint.h>

// Problem constants
#define E_ 64
#define H_ 1024
#define I_ 768
#define T_ 8192

typedef __attribute__((ext_vector_type(4))) float floatx4;
typedef __attribute__((ext_vector_type(8))) short bf16x8;

__device__ inline unsigned short f2bf(float f) {
  union { float f; uint32_t u; } v; v.f = f;
  return (unsigned short)((v.u + 0x7FFFu + ((v.u >> 16) & 1u)) >> 16); // RNE
}
__device__ inline float bf2f(unsigned short s) {
  union { uint32_t u; float f; } v; v.u = ((uint32_t)s) << 16;
  return v.f;
}

// async global->LDS, 16B per lane. LDS dest must be wave-uniform base + lane*16.
__device__ inline void gload16(const void* g, void* l) {
  __builtin_amdgcn_global_load_lds(
      (const __attribute__((address_space(1))) void*)g,
      (__attribute__((address_space(3))) void*)l, 16, 0, 0);
}

// ================= fused prep + weight transform =================
// blocks [0,8192): x fp32->bf16 (+ offs in block 0)
// blocks [8192,13824): weight transform fp32 -> bf16, block-contiguous frag layout:
//   dst[e][nb][kt][chunk i=n_local*4+c][j] = bf16(src[e][kt*32 + c*8 + j][nb*64 + n_local])
// Each (e,kt) block reads a contiguous 32-row slab of the source; writes 16B chunks.
__global__ void k_pt(const float* __restrict__ x, unsigned short* __restrict__ xb,
                     const int* __restrict__ cnts, int* __restrict__ offs,
                     const float* __restrict__ w1, const float* __restrict__ w3,
                     const float* __restrict__ w2, unsigned short* __restrict__ w1t,
                     unsigned short* __restrict__ w3t, unsigned short* __restrict__ w2t) {
  const int tid = threadIdx.x;
  const int b = blockIdx.x;
  if (b < 8192) {
    int i = b * 256 + tid;  // float4 per thread, covers T_*H_ exactly
    float4 v = ((const float4*)x)[i];
    ushort4 o;
    o.x = f2bf(v.x); o.y = f2bf(v.y); o.z = f2bf(v.z); o.w = f2bf(v.w);
    ((ushort4*)xb)[i] = o;
    if (i == 0) {
      int s = 0; offs[0] = 0;
      for (int e = 0; e < E_; ++e) { s += cnts[e]; offs[e + 1] = s; }
    }
    return;
  }
  // weight transform
  const int t2 = b - 8192;
  const float* srcp; unsigned short* dstp; int N, KT, NB, idx;
  if (t2 < 2048)      { srcp = w1; dstp = w1t; N = I_; KT = 32; NB = 12; idx = t2; }
  else if (t2 < 4096) { srcp = w3; dstp = w3t; N = I_; KT = 32; NB = 12; idx = t2 - 2048; }
  else                { srcp = w2; dstp = w2t; N = H_; KT = 24; NB = 16; idx = t2 - 4096; }
  const int e = idx / KT, kt = idx % KT;
  const int K = KT * 32;
  const float* s0 = srcp + (size_t)e * K * N + (size_t)(kt * 32 + (tid & 3) * 8) * N + (tid >> 2);
  unsigned short* d0 = dstp + ((size_t)e * NB * KT + kt) * 2048 + (size_t)tid * 8;
  for (int nb = 0; nb < NB; ++nb) {
    const float* s = s0 + nb * 64;
    uint32_t dw[4];
#pragma unroll
    for (int d2 = 0; d2 < 4; ++d2) {
      float v0 = s[(size_t)(2 * d2) * N];
      float v1 = s[(size_t)(2 * d2 + 1) * N];
      dw[d2] = (uint32_t)f2bf(v0) | ((uint32_t)f2bf(v1) << 16);
    }
    *(uint4*)(d0 + (size_t)nb * KT * 2048) = make_uint4(dw[0], dw[1], dw[2], dw[3]);
  }
}

// ================= GEMM1 (transformed weights): gate/up + SwiGLU -> h =================
// 256x64 tile, BK=32, NK=32. Weights: contiguous bf16 stream, DMA'd straight into
// frag-ready LDS (4-slot ring, counted vmcnt(6), one barrier per step).
// A-frags: register-prefetched one step ahead from L2-resident xb.
__global__ __launch_bounds__(256, 2) void k_gemm1_t(
    const unsigned short* __restrict__ xb, const unsigned short* __restrict__ w1t,
    const unsigned short* __restrict__ w3t, unsigned short* __restrict__ h,
    const int* __restrict__ offs) {
  __shared__ __align__(16) unsigned short Bh[4][2][2048];  // 32 KB ring

  const int tid = threadIdx.x;
  const int wv = tid >> 6;
  const int l = tid & 63;
  const int lq = l >> 4;
  const int ln = l & 15;
  const int bid = ((int)blockIdx.x & 7) * (E_ * (I_ / 64) / 8) + ((int)blockIdx.x >> 3);
  const int e = bid / (I_ / 64);
  const int nb = bid % (I_ / 64);
  const int n0 = nb * 64;
  const int off = offs[e];
  const int cnt = offs[e + 1] - off;

  const unsigned short* w1s = w1t + (size_t)(e * 12 + nb) * (32 * 2048);
  const unsigned short* w3s = w3t + (size_t)(e * 12 + nb) * (32 * 2048);
  const int dmaOff = wv * 512 + l * 8;  // ushort units; wave-uniform base + lane*16B

#define STGB1(kt)                                                            \
  do {                                                                       \
    int _b = (kt) & 3;                                                       \
    gload16(w1s + (size_t)(kt) * 2048 + dmaOff, &Bh[_b][0][dmaOff]);         \
    gload16(w3s + (size_t)(kt) * 2048 + dmaOff, &Bh[_b][1][dmaOff]);         \
  } while (0)

  for (int mb = 0; mb < cnt; mb += 256) {
    const int m_here = (cnt - mb) < 256 ? (cnt - mb) : 256;
    const bool active = (wv * 64) < m_here;

    const unsigned short* aF[4];
#pragma unroll
    for (int mf = 0; mf < 4; ++mf) {
      int row = off + mb + wv * 64 + mf * 16 + ln;
      row = row < (T_ - 1) ? row : (T_ - 1);  // clamp; garbage masked at store
      aF[mf] = xb + (size_t)row * H_ + lq * 8;
    }

    floatx4 accG[4][4], accU[4][4];
#pragma unroll
    for (int i2 = 0; i2 < 4; ++i2)
#pragma unroll
      for (int j2 = 0; j2 < 4; ++j2) {
        accG[i2][j2] = (floatx4){0.f, 0.f, 0.f, 0.f};
        accU[i2][j2] = (floatx4){0.f, 0.f, 0.f, 0.f};
      }

    // prologue: B(0), B(1), A(0)  (order matters for vmcnt accounting)
    STGB1(0);
    STGB1(1);
    bf16x8 afA[4], afB[4];
#pragma unroll
    for (int mf = 0; mf < 4; ++mf) afA[mf] = *(const bf16x8*)(aF[mf]);

    // step body: issue B(kt+2), prefetch A(kt+1) into 'pref', wait B(kt)+A(kt) via
    // counted vmcnt(6) = [B(kt+2)x2 + A(kt+1)x4] allowed in flight. One barrier.
#define STEP1(kt, cons, pref)                                                  \
  do {                                                                         \
    if ((kt) + 2 < 32) STGB1((kt) + 2);                                        \
    if ((kt) + 1 < 32) {                                                       \
      _Pragma("unroll") for (int mf = 0; mf < 4; ++mf)                         \
          pref[mf] = *(const bf16x8*)(aF[mf] + ((kt) + 1) * 32);               \
    }                                                                          \
    asm volatile("s_waitcnt vmcnt(6)" ::: "memory");                           \
    __builtin_amdgcn_s_barrier();                                              \
    asm volatile("" ::: "memory");                                             \
    const unsigned short* B0 = Bh[(kt) & 3][0];                                \
    const unsigned short* B1 = Bh[(kt) & 3][1];                                \
    if (active) {                                                              \
      bf16x8 bG[4], bU[4];                                                     \
      _Pragma("unroll") for (int nf = 0; nf < 4; ++nf) {                       \
        int sl = ((nf * 16 + ln) * 4 + lq) * 8;                                \
        bG[nf] = *(const bf16x8*)&B0[sl];                                      \
        bU[nf] = *(const bf16x8*)&B1[sl];                                      \
      }                                                                        \
      _Pragma("unroll") for (int mf = 0; mf < 4; ++mf)                         \
          _Pragma("unroll") for (int nf = 0; nf < 4; ++nf) {                   \
        accG[mf][nf] =                                                         \
            __builtin_amdgcn_mfma_f32_16x16x32_bf16(cons[mf], bG[nf],          \
                                                    accG[mf][nf], 0, 0, 0);    \
        accU[mf][nf] =                                                         \
            __builtin_amdgcn_mfma_f32_16x16x32_bf16(cons[mf], bU[nf],          \
                                                    accU[mf][nf], 0, 0, 0);    \
      }                                                                        \
    }                                                                          \
    asm volatile("" ::: "memory");                                             \
  } while (0)

    for (int kt = 0; kt < 32; kt += 2) {
      STEP1(kt, afA, afB);
      STEP1(kt + 1, afB, afA);
    }

    if (active) {
#pragma unroll
      for (int mf = 0; mf < 4; ++mf)
#pragma unroll
        for (int nf = 0; nf < 4; ++nf)
#pragma unroll
          for (int r = 0; r < 4; ++r) {
            int row_l = wv * 64 + mf * 16 + lq * 4 + r;  // C/D: row=quad*4+reg, col=lane&15
            if (row_l < m_here) {
              float g = bf2f(f2bf(accG[mf][nf][r]));  // match ref: gate/up rounded to bf16
              float u = bf2f(f2bf(accU[mf][nf][r]));
              float hv = (g / (1.0f + __expf(-g))) * u;  // silu(g)*u
              h[(size_t)(off + mb + row_l) * I_ + n0 + nf * 16 + ln] = f2bf(hv);
            }
          }
    }
    asm volatile("s_waitcnt vmcnt(0)" ::: "memory");  // clean counts for next mb
    __builtin_amdgcn_s_barrier();
  }
#undef STEP1
#undef STGB1
}

// ================= GEMM2 (transformed weights): out = h @ w2 =================
__global__ __launch_bounds__(256, 2) void k_gemm2_t(
    const unsigned short* __restrict__ h, const unsigned short* __restrict__ w2t,
    float* __restrict__ out, const int* __restrict__ offs) {
  __shared__ __align__(16) unsigned short Bh[4][2048];  // 16 KB ring

  const int tid = threadIdx.x;
  const int wv = tid >> 6;
  const int l = tid & 63;
  const int lq = l >> 4;
  const int ln = l & 15;
  const int bid = ((int)blockIdx.x & 7) * (E_ * (H_ / 64) / 8) + ((int)blockIdx.x >> 3);
  const int e = bid / (H_ / 64);
  const int nb = bid % (H_ / 64);
  const int n0 = nb * 64;
  const int off = offs[e];
  const int cnt = offs[e + 1] - off;

  const unsigned short* w2s = w2t + (size_t)(e * 16 + nb) * (24 * 2048);
  const int dmaOff = wv * 512 + l * 8;

#define STGB2(kt) gload16(w2s + (size_t)(kt) * 2048 + dmaOff, &Bh[(kt) & 3][dmaOff])

  for (int mb = 0; mb < cnt; mb += 256) {
    const int m_here = (cnt - mb) < 256 ? (cnt - mb) : 256;
    const bool active = (wv * 64) < m_here;

    const unsigned short* aF[4];
#pragma unroll
    for (int mf = 0; mf < 4; ++mf) {
      int row = off + mb + wv * 64 + mf * 16 + ln;
      row = row < (T_ - 1) ? row : (T_ - 1);
      aF[mf] = h + (size_t)row * I_ + lq * 8;
    }

    floatx4 acc[4][4];
#pragma unroll
    for (int i2 = 0; i2 < 4; ++i2)
#pragma unroll
      for (int j2 = 0; j2 < 4; ++j2) acc[i2][j2] = (floatx4){0.f, 0.f, 0.f, 0.f};

    STGB2(0);
    STGB2(1);
    bf16x8 afA[4], afB[4];
#pragma unroll
    for (int mf = 0; mf < 4; ++mf) afA[mf] = *(const bf16x8*)(aF[mf]);

#define STEP2(kt, cons, pref)                                                  \
  do {                                                                         \
    if ((kt) + 2 < 24) STGB2((kt) + 2);                                        \
    if ((kt) + 1 < 24) {                                                       \
      _Pragma("unroll") for (int mf = 0; mf < 4; ++mf)                         \
          pref[mf] = *(const bf16x8*)(aF[mf] + ((kt) + 1) * 32);               \
    }                                                                          \
    asm volatile("s_waitcnt vmcnt(5)" ::: "memory");                           \
    __builtin_amdgcn_s_barrier();                                              \
    asm volatile("" ::: "memory");                                             \
    const unsigned short* B0 = Bh[(kt) & 3];                                   \
    if (active) {                                                              \
      bf16x8 bF[4];                                                            \
      _Pragma("unroll") for (int nf = 0; nf < 4; ++nf)                         \
          bF[nf] = *(const bf16x8*)&B0[((nf * 16 + ln) * 4 + lq) * 8];         \
      _Pragma("unroll") for (int mf = 0; mf < 4; ++mf)                         \
          _Pragma("unroll") for (int nf = 0; nf < 4; ++nf)                     \
              acc[mf][nf] = __builtin_amdgcn_mfma_f32_16x16x32_bf16(           \
                  cons[mf], bF[nf], acc[mf][nf], 0, 0, 0);                     \
    }                                                                          \
    asm volatile("" ::: "memory");                                             \
  } while (0)

    for (int kt = 0; kt < 24; kt += 2) {
      STEP2(kt, afA, afB);
      STEP2(kt + 1, afB, afA);
    }

    if (active) {
#pragma unroll
      for (int mf = 0; mf < 4; ++mf)
#pragma unroll
        for (int nf = 0; nf < 4; ++nf)
#pragma unroll
          for (int r = 0; r < 4; ++r) {
            int row_l = wv * 64 + mf * 16 + lq * 4 + r;
            if (row_l < m_here)
              out[(size_t)(off + mb + row_l) * H_ + n0 + nf * 16 + ln] = acc[mf][nf][r];
          }
    }
    asm volatile("s_waitcnt vmcnt(0)" ::: "memory");
    __builtin_amdgcn_s_barrier();
  }
#undef STEP2
#undef STGB2
}

// ================= FALLBACK path (round-2 kernels, used if ws too small) =================
__device__ inline int bslot(int n, int c) { return n * 4 + (c ^ ((n >> 1) & 3)); }

__global__ __launch_bounds__(256, 2) void k_gemm1(
    const unsigned short* __restrict__ xb, const float* __restrict__ w1,
    const float* __restrict__ w3, unsigned short* __restrict__ h,
    const int* __restrict__ offs) {
  __shared__ __align__(16) float Bf[2][2][32 * 64];
  __shared__ __align__(16) unsigned short Bh[2][64 * 32];

  const int tid = threadIdx.x;
  const int wv = tid >> 6;
  const int l = tid & 63;
  const int lq = l >> 4;
  const int ln = l & 15;
  const int bid = ((int)blockIdx.x & 7) * (E_ * (I_ / 64) / 8) + ((int)blockIdx.x >> 3);
  const int e = bid / (I_ / 64);
  const int n0 = (bid % (I_ / 64)) * 64;
  const int off = offs[e];
  const int cnt = offs[e + 1] - off;
  const int cn = tid & 63;
  const int ck = tid >> 6;
  const float* b1p = w1 + (size_t)e * (H_ * I_) + (size_t)(tid >> 4) * I_ + n0 + (tid & 15) * 4;
  const float* b3p = w3 + (size_t)e * (H_ * I_) + (size_t)(tid >> 4) * I_ + n0 + (tid & 15) * 4;

  for (int mb = 0; mb < cnt; mb += 256) {
    const int m_here = (cnt - mb) < 256 ? (cnt - mb) : 256;
    const bool active = (wv * 64) < m_here;
    const unsigned short* aF[4];
#pragma unroll
    for (int mf = 0; mf < 4; ++mf) {
      int row = off + mb + wv * 64 + mf * 16 + ln;
      row = row < (T_ - 1) ? row : (T_ - 1);
      aF[mf] = xb + (size_t)row * H_ + lq * 8;
    }
    auto STGB = [&](int kt, int buf) {
#pragma unroll
      for (int r = 0; r < 2; ++r) {
        gload16(b1p + (size_t)(kt * 32 + r * 16) * I_, &Bf[buf][0][tid * 4 + r * 1024]);
        gload16(b3p + (size_t)(kt * 32 + r * 16) * I_, &Bf[buf][1][tid * 4 + r * 1024]);
      }
    };
    floatx4 accG[4][4], accU[4][4];
#pragma unroll
    for (int i2 = 0; i2 < 4; ++i2)
#pragma unroll
      for (int j2 = 0; j2 < 4; ++j2) {
        accG[i2][j2] = (floatx4){0.f, 0.f, 0.f, 0.f};
        accU[i2][j2] = (floatx4){0.f, 0.f, 0.f, 0.f};
      }
    const int NK = H_ / 32;
    STGB(0, 0);
    STGB(1, 1);
    for (int kt = 0; kt < NK; ++kt) {
      const int cur = kt & 1;
      if (kt == NK - 1) asm volatile("s_waitcnt vmcnt(0)" ::: "memory");
      else              asm volatile("s_waitcnt vmcnt(4)" ::: "memory");
      __builtin_amdgcn_s_barrier();
      asm volatile("" ::: "memory");
#pragma unroll
      for (int m = 0; m < 2; ++m) {
        uint32_t dw[4];
#pragma unroll
        for (int d = 0; d < 4; ++d) {
          float v0 = Bf[cur][m][(ck * 8 + 2 * d) * 64 + cn];
          float v1 = Bf[cur][m][(ck * 8 + 2 * d + 1) * 64 + cn];
          dw[d] = (uint32_t)f2bf(v0) | ((uint32_t)f2bf(v1) << 16);
        }
        *(uint4*)&Bh[m][(size_t)bslot(cn, ck) * 8] = make_uint4(dw[0], dw[1], dw[2], dw[3]);
      }
      asm volatile("s_waitcnt lgkmcnt(0)" ::: "memory");
      __builtin_amdgcn_s_barrier();
      asm volatile("" ::: "memory");
      bf16x8 af[4];
      if (active) {
#pragma unroll
        for (int mf = 0; mf < 4; ++mf) af[mf] = *(const bf16x8*)(aF[mf] + kt * 32);
      }
      asm volatile("" ::: "memory");
      if (kt + 2 < NK) STGB(kt + 2, cur);
      asm volatile("" ::: "memory");
      if (active) {
        bf16x8 bG[4], bU[4];
#pragma unroll
        for (int nf = 0; nf < 4; ++nf) {
          const int sl = bslot(nf * 16 + ln, lq) * 8;
          bG[nf] = *(const bf16x8*)&Bh[0][sl];
          bU[nf] = *(const bf16x8*)&Bh[1][sl];
        }
#pragma unroll
        for (int mf = 0; mf < 4; ++mf)
#pragma unroll
          for (int nf = 0; nf < 4; ++nf) {
            accG[mf][nf] = __builtin_amdgcn_mfma_f32_16x16x32_bf16(af[mf], bG[nf], accG[mf][nf], 0, 0, 0);
            accU[mf][nf] = __builtin_amdgcn_mfma_f32_16x16x32_bf16(af[mf], bU[nf], accU[mf][nf], 0, 0, 0);
          }
      }
    }
    if (active) {
#pragma unroll
      for (int mf = 0; mf < 4; ++mf)
#pragma unroll
        for (int nf = 0; nf < 4; ++nf)
#pragma unroll
          for (int r = 0; r < 4; ++r) {
            int row_l = wv * 64 + mf * 16 + lq * 4 + r;
            if (row_l < m_here) {
              float g = bf2f(f2bf(accG[mf][nf][r]));
              float u = bf2f(f2bf(accU[mf][nf][r]));
              float hv = (g / (1.0f + __expf(-g))) * u;
              h[(size_t)(off + mb + row_l) * I_ + n0 + nf * 16 + ln] = f2bf(hv);
            }
          }
    }
    asm volatile("s_waitcnt vmcnt(0)" ::: "memory");
  }
}

__global__ __launch_bounds__(256, 2) void k_gemm2(
    const unsigned short* __restrict__ h, const float* __restrict__ w2,
    float* __restrict__ out, const int* __restrict__ offs) {
  __shared__ __align__(16) float Bf[2][32 * 64];
  __shared__ __align__(16) unsigned short Bh[64 * 32];

  const int tid = threadIdx.x;
  const int wv = tid >> 6;
  const int l = tid & 63;
  const int lq = l >> 4;
  const int ln = l & 15;
  const int bid = ((int)blockIdx.x & 7) * (E_ * (H_ / 64) / 8) + ((int)blockIdx.x >> 3);
  const int e = bid / (H_ / 64);
  const int n0 = (bid % (H_ / 64)) * 64;
  const int off = offs[e];
  const int cnt = offs[e + 1] - off;
  const int cn = tid & 63;
  const int ck = tid >> 6;
  const float* b2p = w2 + (size_t)e * (I_ * H_) + (size_t)(tid >> 4) * H_ + n0 + (tid & 15) * 4;

  for (int mb = 0; mb < cnt; mb += 256) {
    const int m_here = (cnt - mb) < 256 ? (cnt - mb) : 256;
    const bool active = (wv * 64) < m_here;
    const unsigned short* aF[4];
#pragma unroll
    for (int mf = 0; mf < 4; ++mf) {
      int row = off + mb + wv * 64 + mf * 16 + ln;
      row = row < (T_ - 1) ? row : (T_ - 1);
      aF[mf] = h + (size_t)row * I_ + lq * 8;
    }
    auto STGB = [&](int kt, int buf) {
#pragma unroll
      for (int r = 0; r < 2; ++r)
        gload16(b2p + (size_t)(kt * 32 + r * 16) * H_, &Bf[buf][tid * 4 + r * 1024]);
    };
    floatx4 acc[4][4];
#pragma unroll
    for (int i2 = 0; i2 < 4; ++i2)
#pragma unroll
      for (int j2 = 0; j2 < 4; ++j2) acc[i2][j2] = (floatx4){0.f, 0.f, 0.f, 0.f};
    const int NK = I_ / 32;
    STGB(0, 0);
    STGB(1, 1);
    for (int kt = 0; kt < NK; ++kt) {
      const int cur = kt & 1;
      if (kt == NK - 1) asm volatile("s_waitcnt vmcnt(0)" ::: "memory");
      else              asm volatile("s_waitcnt vmcnt(2)" ::: "memory");
      __builtin_amdgcn_s_barrier();
      asm volatile("" ::: "memory");
      {
        uint32_t dw[4];
#pragma unroll
        for (int d = 0; d < 4; ++d) {
          float v0 = Bf[cur][(ck * 8 + 2 * d) * 64 + cn];
          float v1 = Bf[cur][(ck * 8 + 2 * d + 1) * 64 + cn];
          dw[d] = (uint32_t)f2bf(v0) | ((uint32_t)f2bf(v1) << 16);
        }
        *(uint4*)&Bh[(size_t)bslot(cn, ck) * 8] = make_uint4(dw[0], dw[1], dw[2], dw[3]);
      }
      asm volatile("s_waitcnt lgkmcnt(0)" ::: "memory");
      __builtin_amdgcn_s_barrier();
      asm volatile("" ::: "memory");
      bf16x8 af[4];
      if (active) {
#pragma unroll
        for (int mf = 0; mf < 4; ++mf) af[mf] = *(const bf16x8*)(aF[mf] + kt * 32);
      }
      asm volatile("" ::: "memory");
      if (kt + 2 < NK) STGB(kt + 2, cur);
      asm volatile("" ::: "memory");
      if (active) {
        bf16x8 bF[4];
#pragma unroll
        for (int nf = 0; nf < 4; ++nf)
          bF[nf] = *(const bf16x8*)&Bh[(size_t)bslot(nf * 16 + ln, lq) * 8];
#pragma unroll
        for (int mf = 0; mf < 4; ++mf)
#pragma unroll
          for (int nf = 0; nf < 4; ++nf)
            acc[mf][nf] = __builtin_amdgcn_mfma_f32_16x16x32_bf16(af[mf], bF[nf], acc[mf][nf], 0, 0, 0);
      }
    }
    if (active) {
#pragma unroll
      for (int mf = 0; mf < 4; ++mf)
#pragma unroll
        for (int nf = 0; nf < 4; ++nf)
#pragma unroll
          for (int r = 0; r < 4; ++r) {
            int row_l = wv * 64 + mf * 16 + lq * 4 + r;
            if (row_l < m_here)
              out[(size_t)(off + mb + row_l) * H_ + n0 + nf * 16 + ln] = acc[mf][nf][r];
          }
    }
    asm volatile("s_waitcnt vmcnt(0)" ::: "memory");
  }
}

extern "C" void kernel_launch(void* const* d_in, const int* in_sizes, int n_in,
                              void* d_out, int out_size, void* d_ws, size_t ws_size,
                              hipStream_t stream) {
  const float* x  = (const float*)d_in[0];
  const float* w1 = (const float*)d_in[1];
  const float* w2 = (const float*)d_in[2];
  const float* w3 = (const float*)d_in[3];
  const int* cnts = (const int*)d_in[4];
  float* out = (float*)d_out;

  char* ws = (char*)d_ws;
  const size_t XB = (size_t)T_ * H_ * 2;       // 16 MB
  const size_t HB = (size_t)T_ * I_ * 2;       // 12 MB
  const size_t WT = (size_t)E_ * H_ * I_ * 2;  // 100.66 MB per transformed matrix
  int* offs = (int*)ws;
  unsigned short* xb = (unsigned short*)(ws + 1024);
  unsigned short* h  = (unsigned short*)(ws + 1024 + XB);
  const size_t need = 1024 + XB + HB + 3 * WT;

  if (ws_size >= need) {
    unsigned short* w1t = (unsigned short*)(ws + 1024 + XB + HB);
    unsigned short* w3t = (unsigned short*)(ws + 1024 + XB + HB + WT);
    unsigned short* w2t = (unsigned short*)(ws + 1024 + XB + HB + 2 * WT);
    k_pt<<<8192 + 5632, 256, 0, stream>>>(x, xb, cnts, offs, w1, w3, w2, w1t, w3t, w2t);
    k_gemm1_t<<<E_ * (I_ / 64), 256, 0, stream>>>(xb, w1t, w3t, h, offs);
    k_gemm2_t<<<E_ * (H_ / 64), 256, 0, stream>>>(h, w2t, out, offs);
  } else {
    // fallback: in-kernel fp32 staging (round-2 path)
    k_pt<<<8192, 256, 0, stream>>>(x, xb, cnts, offs, w1, w3, w2, xb, xb, xb);
    k_gemm1<<<E_ * (I_ / 64), 256, 0, stream>>>(xb, w1, w3, h, offs);
    k_gemm2<<<E_ * (H_ / 64), 256, 0, stream>>>(h, w2, out, offs);
  }
}